// Round 4
// baseline (265.307 us; speedup 1.0000x reference)
//
#include <hip/hip_runtime.h>
#include <hip/hip_bf16.h>

// Sparse MoE: T=2048, D=1024, E=8 routed (H=768, top-2) + shared GatedMLP (1536 hidden).
// R4: shared MLP decomposed into 2 pseudo-experts of routed shape (H=768, w=1, all tokens)
// -> 10 uniform experts, two fat 128x128 BK=64 MFMA GEMM kernels (fc1 fused silu+scale,
// fc2 atomicAdd into out zeroed by gate). Gate absorbs x->bf16. 5 kernels total.

typedef short bf16x8 __attribute__((ext_vector_type(8)));
typedef float f32x4 __attribute__((ext_vector_type(4)));

__device__ __forceinline__ unsigned short f2b(float f) {
    __hip_bfloat16 h = __float2bfloat16(f);
    return *reinterpret_cast<unsigned short*>(&h);
}

__device__ __forceinline__ void ldst16(const unsigned short* g, unsigned short* l) {
    __builtin_amdgcn_global_load_lds(
        (const __attribute__((address_space(1))) unsigned int*)g,
        (__attribute__((address_space(3))) unsigned int*)l, 16, 0, 0);
}

__device__ __forceinline__ void cvt8(const float* s, unsigned short* d, int j) {
    const float4* sp = reinterpret_cast<const float4*>(s) + (size_t)j * 2;
    float4 v0 = sp[0], v1 = sp[1];
    union { unsigned short u[8]; uint4 v; } o;
    o.u[0]=f2b(v0.x); o.u[1]=f2b(v0.y); o.u[2]=f2b(v0.z); o.u[3]=f2b(v0.w);
    o.u[4]=f2b(v1.x); o.u[5]=f2b(v1.y); o.u[6]=f2b(v1.z); o.u[7]=f2b(v1.w);
    *(reinterpret_cast<uint4*>(d) + j) = o.v;
}

// ---------------- weight conversion fp32->bf16 ----------------
__global__ __launch_bounds__(256) void k_conv(const float* __restrict__ W1,
                                              const float* __restrict__ Ws1,
                                              const float* __restrict__ W2,
                                              const float* __restrict__ Ws2,
                                              unsigned short* __restrict__ W1b,
                                              unsigned short* __restrict__ Ws1b,
                                              unsigned short* __restrict__ W2b,
                                              unsigned short* __restrict__ Ws2b) {
    int i = blockIdx.x * 256 + threadIdx.x;
    if (i < 1572864)       cvt8(W1,  W1b,  i);
    else if (i < 1966080)  cvt8(Ws1, Ws1b, i - 1572864);
    else if (i < 2752512)  cvt8(W2,  W2b,  i - 1966080);
    else if (i < 2949120)  cvt8(Ws2, Ws2b, i - 2752512);
}

// ---------------- gate: logits+softmax+top2, x->bf16, zero out ----------------
__global__ __launch_bounds__(256) void k_gate(const float* __restrict__ x,
                                              const float* __restrict__ gw,
                                              unsigned short* __restrict__ xb,
                                              int* __restrict__ topk_e,
                                              float* __restrict__ topk_w,
                                              float* __restrict__ out) {
    const int t = blockIdx.x, tid = threadIdx.x;
    const int lane = tid & 63, w = tid >> 6;
    __shared__ float red[4][8];
    __shared__ float sc[8];

    float4 v = reinterpret_cast<const float4*>(x + (size_t)t * 1024)[tid];
    union { unsigned short u[4]; ushort2 h2[2]; } o;
    o.u[0]=f2b(v.x); o.u[1]=f2b(v.y); o.u[2]=f2b(v.z); o.u[3]=f2b(v.w);
    reinterpret_cast<ushort4*>(xb + (size_t)t * 1024)[tid] = *(ushort4*)o.u;

    float p[8];
    for (int e = 0; e < 8; e++) {
        float4 g = reinterpret_cast<const float4*>(gw + (size_t)e * 1024)[tid];
        p[e] = v.x*g.x + v.y*g.y + v.z*g.z + v.w*g.w;
    }
    for (int e = 0; e < 8; e++)
        for (int off = 32; off > 0; off >>= 1) p[e] += __shfl_down(p[e], off, 64);
    if (lane == 0)
        for (int e = 0; e < 8; e++) red[w][e] = p[e];
    __syncthreads();
    if (tid < 8) sc[tid] = red[0][tid] + red[1][tid] + red[2][tid] + red[3][tid];
    __syncthreads();
    if (tid == 0) {
        float m = sc[0];
        for (int e = 1; e < 8; e++) m = fmaxf(m, sc[e]);
        float ex[8], sum = 0.f;
        for (int e = 0; e < 8; e++) { ex[e] = expf(sc[e] - m); sum += ex[e]; }
        float inv = 1.f / sum;
        int i1 = 0;
        for (int e = 1; e < 8; e++) if (sc[e] > sc[i1]) i1 = e;
        int i2 = -1; float s2 = -1e30f;
        for (int e = 0; e < 8; e++) if (e != i1 && sc[e] > s2) { s2 = sc[e]; i2 = e; }
        topk_e[t * 2]     = i1; topk_w[t * 2]     = ex[i1] * inv;
        topk_e[t * 2 + 1] = i2; topk_w[t * 2 + 1] = ex[i2] * inv;
    }
    reinterpret_cast<float4*>(out + (size_t)t * 1024)[tid] = (float4){0.f, 0.f, 0.f, 0.f};
}

// ---------------- counting sort; experts 8,9 = all tokens, weight 1 ----------------
__global__ __launch_bounds__(256) void k_sort(const int* __restrict__ topk_e,
                                              const float* __restrict__ topk_w,
                                              int* __restrict__ tokslot,
                                              float* __restrict__ wroute,
                                              int* __restrict__ cnt) {
    __shared__ int lcnt[8], lcur[8];
    int tid = threadIdx.x;
    if (tid < 8) { lcnt[tid] = 0; lcur[tid] = 0; }
    __syncthreads();
    for (int i = tid; i < 4096; i += 256) atomicAdd(&lcnt[topk_e[i]], 1);
    __syncthreads();
    if (tid < 8) cnt[tid] = lcnt[tid];
    for (int i = tid; i < 4096; i += 256) {
        int e = topk_e[i];
        int pos = atomicAdd(&lcur[e], 1);
        tokslot[e * 2048 + pos] = i;          // i = t*2 + slot
        wroute[e * 2048 + pos]  = topk_w[i];
    }
    for (int i = tid; i < 2048; i += 256) {
        tokslot[8 * 2048 + i] = i << 1;  wroute[8 * 2048 + i] = 1.0f;
        tokslot[9 * 2048 + i] = i << 1;  wroute[9 * 2048 + i] = 1.0f;
    }
}

// ---------------- unified fc1: 10 experts, 128 tok x 128 h-cols, BK=64 ----------------
// Grid: bid = mt*6 + ht; mt over per-expert M-tiles (prefix over cnt, shared=16 each).
__global__ __launch_bounds__(256) void k_fc1u(const unsigned short* __restrict__ xb,
                                              const unsigned short* __restrict__ W1b,
                                              const unsigned short* __restrict__ Ws1b,
                                              const int* __restrict__ tokslot,
                                              const float* __restrict__ wroute,
                                              const int* __restrict__ cnt,
                                              unsigned short* __restrict__ act) {
    __shared__ alignas(16) unsigned short As[128 * 64];   // 16KB
    __shared__ alignas(16) unsigned short Bs[256 * 64];   // 32KB
    const int tid = threadIdx.x, lane = tid & 63, w = tid >> 6;
    const int wr = w >> 1, wc = w & 1;
    const int mt = blockIdx.x / 6, ht = blockIdx.x % 6;

    int pre = 0, sel = -1, base = 0;
    for (int ee = 0; ee < 10; ee++) {
        int til = (ee < 8) ? ((cnt[ee] + 127) >> 7) : 16;
        if (sel < 0 && mt < pre + til) { sel = ee; base = pre; }
        pre += til;
    }
    if (sel < 0) return;
    const int e = sel, m0 = (mt - base) * 128, h0 = ht * 128;
    const int Te = (e < 8) ? cnt[e] : 2048;
    const unsigned short* Bp = (e < 8) ? (W1b + (size_t)e * 1536 * 1024)
                                       : (Ws1b + (size_t)(e - 8) * 768 * 1024);
    const int gOff = (e < 8) ? 768 : 1536;

    const int kc = tid & 7;
    int aoff[4], boff[8];
    for (int q = 0; q < 4; q++) {                 // A: 128 rows x 8 chunks
        int row = q * 32 + (tid >> 3);
        int idx = m0 + row;
        int tk = (idx < Te) ? (tokslot[e * 2048 + idx] >> 1) : 0;
        aoff[q] = tk * 1024 + ((kc ^ (row & 7)) << 3);
    }
    for (int q = 0; q < 8; q++) {                 // B: 256 rows (128 y + 128 g)
        int row = q * 32 + (tid >> 3);
        int grow = (row < 128) ? (h0 + row) : (gOff + h0 + row - 128);
        boff[q] = grow * 1024 + ((kc ^ (row & 7)) << 3);
    }

    f32x4 accy[4][4], accg[4][4];
    for (int i = 0; i < 4; i++)
        for (int j = 0; j < 4; j++) {
            accy[i][j] = (f32x4){0.f, 0.f, 0.f, 0.f};
            accg[i][j] = (f32x4){0.f, 0.f, 0.f, 0.f};
        }

    for (int k0 = 0; k0 < 1024; k0 += 64) {
        for (int q = 0; q < 4; q++) ldst16(xb + aoff[q] + k0, As + (q * 256 + tid) * 8);
        for (int q = 0; q < 8; q++) ldst16(Bp + boff[q] + k0, Bs + (q * 256 + tid) * 8);
        __syncthreads();
        for (int kh = 0; kh < 2; kh++) {
            const int cq = kh * 4 + (lane >> 4);
            bf16x8 a[4], by[4], bg[4];
            for (int i = 0; i < 4; i++) {
                int r = 64 * wr + 16 * i + (lane & 15);
                a[i] = *(const bf16x8*)&As[r * 64 + ((cq ^ (r & 7)) << 3)];
            }
            for (int j = 0; j < 4; j++) {
                int r = 64 * wc + 16 * j + (lane & 15);
                by[j] = *(const bf16x8*)&Bs[r * 64 + ((cq ^ (r & 7)) << 3)];
                int rg = 128 + r;
                bg[j] = *(const bf16x8*)&Bs[rg * 64 + ((cq ^ (rg & 7)) << 3)];
            }
            for (int i = 0; i < 4; i++)
                for (int j = 0; j < 4; j++) {
                    accy[i][j] = __builtin_amdgcn_mfma_f32_16x16x32_bf16(a[i], by[j], accy[i][j], 0, 0, 0);
                    accg[i][j] = __builtin_amdgcn_mfma_f32_16x16x32_bf16(a[i], bg[j], accg[i][j], 0, 0, 0);
                }
        }
        __syncthreads();
    }

    for (int i = 0; i < 4; i++)
        for (int r = 0; r < 4; r++) {
            int irow = m0 + 64 * wr + 16 * i + ((lane >> 4) << 2) + r;
            if (irow >= Te) continue;
            float sw = wroute[e * 2048 + irow];
            for (int j = 0; j < 4; j++) {
                float y = accy[i][j][r], g = accg[i][j][r];
                float sg = g / (1.0f + __expf(-g));
                int col = h0 + 64 * wc + 16 * j + (lane & 15);
                act[((size_t)e * 2048 + irow) * 768 + col] = f2b(sw * y * sg);
            }
        }
}

// ---------------- unified fc2: 10 experts, 128x128, K=768, atomicAdd into out ----------
__global__ __launch_bounds__(256) void k_fc2u(const unsigned short* __restrict__ act,
                                              const unsigned short* __restrict__ W2b,
                                              const unsigned short* __restrict__ Ws2b,
                                              const int* __restrict__ tokslot,
                                              const int* __restrict__ cnt,
                                              float* __restrict__ out) {
    __shared__ alignas(16) unsigned short As[128 * 64];   // 16KB
    __shared__ alignas(16) unsigned short Bs[128 * 64];   // 16KB
    const int tid = threadIdx.x, lane = tid & 63, w = tid >> 6;
    const int wr = w >> 1, wc = w & 1;
    const int mt = blockIdx.x >> 3, nt = blockIdx.x & 7;

    int pre = 0, sel = -1, base = 0;
    for (int ee = 0; ee < 10; ee++) {
        int til = (ee < 8) ? ((cnt[ee] + 127) >> 7) : 16;
        if (sel < 0 && mt < pre + til) { sel = ee; base = pre; }
        pre += til;
    }
    if (sel < 0) return;
    const int e = sel, m0 = (mt - base) * 128, n0 = nt * 128;
    const int Te = (e < 8) ? cnt[e] : 2048;
    const unsigned short* Ab = act + (size_t)e * 2048 * 768;
    const unsigned short* Bb = (e < 8) ? (W2b + (size_t)e * 1024 * 768)
                                       : (Ws2b + (size_t)(e - 8) * 768);
    const int bstride = (e < 8) ? 768 : 1536;

    const int kc = tid & 7;
    int aoff[4], boff[4];
    for (int q = 0; q < 4; q++) {
        int row = q * 32 + (tid >> 3);
        int ko = (kc ^ (row & 7)) << 3;
        aoff[q] = (m0 + row) * 768 + ko;
        boff[q] = (n0 + row) * bstride + ko;
    }

    f32x4 acc[4][4];
    for (int i = 0; i < 4; i++)
        for (int j = 0; j < 4; j++) acc[i][j] = (f32x4){0.f, 0.f, 0.f, 0.f};

    for (int k0 = 0; k0 < 768; k0 += 64) {
        for (int q = 0; q < 4; q++) {
            ldst16(Ab + aoff[q] + k0, As + (q * 256 + tid) * 8);
            ldst16(Bb + boff[q] + k0, Bs + (q * 256 + tid) * 8);
        }
        __syncthreads();
        for (int kh = 0; kh < 2; kh++) {
            const int cq = kh * 4 + (lane >> 4);
            bf16x8 a[4], b[4];
            for (int i = 0; i < 4; i++) {
                int r = 64 * wr + 16 * i + (lane & 15);
                a[i] = *(const bf16x8*)&As[r * 64 + ((cq ^ (r & 7)) << 3)];
            }
            for (int j = 0; j < 4; j++) {
                int r = 64 * wc + 16 * j + (lane & 15);
                b[j] = *(const bf16x8*)&Bs[r * 64 + ((cq ^ (r & 7)) << 3)];
            }
            for (int i = 0; i < 4; i++)
                for (int j = 0; j < 4; j++)
                    acc[i][j] = __builtin_amdgcn_mfma_f32_16x16x32_bf16(a[i], b[j], acc[i][j], 0, 0, 0);
        }
        __syncthreads();
    }

    for (int i = 0; i < 4; i++)
        for (int r = 0; r < 4; r++) {
            int irow = m0 + 64 * wr + 16 * i + ((lane >> 4) << 2) + r;
            if (irow >= Te) continue;
            int t = tokslot[e * 2048 + irow] >> 1;
            for (int j = 0; j < 4; j++) {
                int col = n0 + 64 * wc + 16 * j + (lane & 15);
                atomicAdd(out + (size_t)t * 1024 + col, acc[i][j][r]);
            }
        }
}

extern "C" void kernel_launch(void* const* d_in, const int* in_sizes, int n_in,
                              void* d_out, int out_size, void* d_ws, size_t ws_size,
                              hipStream_t stream) {
    const float* x   = (const float*)d_in[0];
    const float* gw  = (const float*)d_in[1];
    const float* W1  = (const float*)d_in[2];
    const float* W2  = (const float*)d_in[3];
    const float* Ws1 = (const float*)d_in[4];
    const float* Ws2 = (const float*)d_in[5];
    float* out = (float*)d_out;

    char* ws = (char*)d_ws;
    unsigned short* xb    = (unsigned short*)(ws + 0);          //  4,194,304
    unsigned short* W1b   = (unsigned short*)(ws + 4194304);    // 25,165,824
    unsigned short* Ws1b  = (unsigned short*)(ws + 29360128);   //  6,291,456
    unsigned short* W2b   = (unsigned short*)(ws + 35651584);   // 12,582,912
    unsigned short* Ws2b  = (unsigned short*)(ws + 48234496);   //  3,145,728
    unsigned short* act   = (unsigned short*)(ws + 51380224);   // 31,457,280 (10x2048x768)
    int*            topk_e  = (int*)(ws + 82837504);            //     16,384
    float*          topk_w  = (float*)(ws + 82853888);          //     16,384
    int*            tokslot = (int*)(ws + 82870272);            //     81,920 (10x2048)
    float*          wroute  = (float*)(ws + 82952192);          //     81,920
    int*            cnt     = (int*)(ws + 83034112);            //         32

    k_conv<<<11520, 256, 0, stream>>>(W1, Ws1, W2, Ws2, W1b, Ws1b, W2b, Ws2b);
    k_gate<<<2048, 256, 0, stream>>>(x, gw, xb, topk_e, topk_w, out);
    k_sort<<<1, 256, 0, stream>>>(topk_e, topk_w, tokslot, wroute, cnt);
    k_fc1u<<<426, 256, 0, stream>>>(xb, W1b, Ws1b, tokslot, wroute, cnt, act);
    k_fc2u<<<568, 256, 0, stream>>>(act, W2b, Ws2b, tokslot, cnt, out);
}